// Round 16
// baseline (260.137 us; speedup 1.0000x reference)
//
#include <hip/hip_runtime.h>

// CRF-RNN mean-field, 2 iterations, N=8192 (32x16x16), C=4.
// Spatial: exactly separable -> 3 dense 1-D convs. Bilateral: N^2, split-K.
// r16 = r6's measured-best structure (4 dispatches, 2048+32 fused, 2-row
// h-sharing, KS=128) with the inner loop's LDS traffic cut 3x b128 -> b128+b64:
// j-position features are index-derived (gh block-uniform folded into the base,
// gw per-16, gd incremental), record = {c0,c1,c2,nj} + bf16x4 sm. Unrolled
// inner loop => LDS immediate offsets, zero address VALU. Model: 0.44 cyc/pair
// VALU-bound (was LDS-return-bound 1.45x at 3x b128 broadcast reads).

#define HH 32
#define WW 16
#define DDD 16
#define NN (HH * WW * DDD)    // 8192
#define KS 128                // split-K over j
#define JC (NN / KS)          // 64 j per block (one h-slab quarter: 4 w-groups)
#define CONVB 32
#define GB 2048               // 16 i-tiles (512 rows) x KS
#define L2E 1.4426950408889634f
#define C18 (L2E / 18.0f)     // spatial: exp(-d^2/18) == exp2(-d^2*C18)
#define SQL2E 1.2011224087864498f   // sqrt(log2 e): feats pre-scaled, exp==exp2
#define SB (SQL2E / 8.0f)     // THETA_ALPHA
#define SC (SQL2E / 0.5f)     // THETA_BETA

#if __has_builtin(__builtin_amdgcn_exp2f)
#define EXP2(x) __builtin_amdgcn_exp2f(x)
#else
#define EXP2(x) exp2f(x)
#endif

__device__ __forceinline__ unsigned int cvtpk(float lo, float hi) {
    unsigned int r;
    asm("v_cvt_pk_bf16_f32 %0, %1, %2" : "=v"(r) : "v"(lo), "v"(hi));
    return r;
}
__device__ __forceinline__ float bfLO(unsigned int u) {
    return __uint_as_float(u << 16);
}
__device__ __forceinline__ float bfHI(unsigned int u) {
    return __uint_as_float(u & 0xFFFF0000u);
}

// blocks [0,CONVB): spatial conv D,W (inline softmax).  blocks [CONVB..): bilat.
__global__ __launch_bounds__(256, 8) void fused(
    const float* __restrict__ qin,   // [N][4] current q (u on iter 1)
    const float* __restrict__ rgb,   // [N][3]
    float* __restrict__ part,        // [KS][N*4] bilateral partial numerators
    float* __restrict__ tmp)         // [N][4] d,w-convolved softmax
{
    __shared__ float convL[2048];    // conv: A[1024]|B[1024]
    __shared__ float4 REC[JC];       // bilat: {c0,c1,c2,nj}
    __shared__ uint2  SMA[JC];       // bilat: bf16x4 softmax
    int tid = threadIdx.x;

    if (blockIdx.x >= CONVB) {
        // ---------------- bilateral N^2, 2 rows/thread (h-delta) ----------------
        int b = blockIdx.x - CONVB;
        int ib = b >> 7;                 // 16 i-tiles of 512 rows
        int kc = b & (KS - 1);
        int i0 = ib * 512 + tid;         // h = 2*ib
        int i1 = i0 + 256;               // h = 2*ib + 1
        int j0 = kc * JC;

        // stage 64 j-records (threads 0..63)
        if (tid < JC) {
            int j = j0 + tid;
            int jh = j >> 8, jr = j & 255;
            float gh = (float)(jh + 1) * SB;
            float gw = (float)((jr >> 4) + 1) * SB;
            float gd = (float)((jr & 15) + 1) * SB;
            float e0 = rgb[3 * j + 0] * SC;
            float e1 = rgb[3 * j + 1] * SC;
            float e2 = rgb[3 * j + 2] * SC;
            float nj = -0.5f * (gh * gh + gw * gw + gd * gd +
                                e0 * e0 + e1 * e1 + e2 * e2);
            REC[tid] = make_float4(e0, e1, e2, nj);
            float4 q = ((const float4*)qin)[j];
            float m = fmaxf(fmaxf(q.x, q.y), fmaxf(q.z, q.w));
            float s0 = EXP2((q.x - m) * L2E), s1 = EXP2((q.y - m) * L2E);
            float s2 = EXP2((q.z - m) * L2E), s3 = EXP2((q.w - m) * L2E);
            float rs = 1.0f / (s0 + s1 + s2 + s3);
            SMA[tid] = make_uint2(cvtpk(s0 * rs, s1 * rs), cvtpk(s2 * rs, s3 * rs));
        }

        // i-side constants
        float fw = (float)((tid >> 4) + 1) * SB;
        float fd = (float)((tid & 15) + 1) * SB;
        float fh0 = (float)(2 * ib + 1) * SB;
        float c00 = rgb[3 * i0 + 0] * SC;
        float c01 = rgb[3 * i0 + 1] * SC;
        float c02 = rgb[3 * i0 + 2] * SC;
        float c10 = rgb[3 * i1 + 0] * SC;
        float c11 = rgb[3 * i1 + 1] * SC;
        float c12 = rgb[3 * i1 + 2] * SC;
        float dc0 = c10 - c00, dc1 = c11 - c01, dc2 = c12 - c02;
        float fwd2 = fw * fw + fd * fd;
        float fh1 = fh0 + SB;
        float nn0 = -0.5f * (fh0 * fh0 + fwd2 + c00 * c00 + c01 * c01 + c02 * c02);
        float nn1 = -0.5f * (fh1 * fh1 + fwd2 + c10 * c10 + c11 * c11 + c12 * c12);

        float ghs = (float)((j0 >> 8) + 1) * SB;   // block-uniform j-h feature
        float nnb0 = fmaf(fh0, ghs, nn0);          // base for row 0
        float du = (nn1 - nn0) + SB * ghs;         // row1 = row0 + du + dc.e

        float a0 = 0, a1 = 0, a2 = 0, a3 = 0;
        float b0 = 0, b1 = 0, b2 = 0, b3 = 0;

        __syncthreads();

        int w0g = (j0 >> 4) & 15;
        for (int jw = 0; jw < 4; ++jw) {
            float gws = (float)(w0g + jw + 1) * SB;
            float fwg = fw * gws;
            float gds = SB;
            #pragma unroll
            for (int jd = 0; jd < 16; ++jd) {
                int jj = jw * 16 + jd;
                float4 r4 = REC[jj];
                uint2 sp = SMA[jj];
                float g0 = nnb0 + r4.w + fwg;
                g0 = fmaf(fd, gds, g0);
                g0 = fmaf(c00, r4.x, g0);
                g0 = fmaf(c01, r4.y, g0);
                g0 = fmaf(c02, r4.z, g0);
                float g1 = g0 + du;
                g1 = fmaf(dc0, r4.x, g1);
                g1 = fmaf(dc1, r4.y, g1);
                g1 = fmaf(dc2, r4.z, g1);
                float w0 = EXP2(g0);
                float w1 = EXP2(g1);
                float s0 = bfLO(sp.x), s1 = bfHI(sp.x);
                float s2 = bfLO(sp.y), s3 = bfHI(sp.y);
                a0 = fmaf(w0, s0, a0); a1 = fmaf(w0, s1, a1);
                a2 = fmaf(w0, s2, a2); a3 = fmaf(w0, s3, a3);
                b0 = fmaf(w1, s0, b0); b1 = fmaf(w1, s1, b1);
                b2 = fmaf(w1, s2, b2); b3 = fmaf(w1, s3, b3);
                gds += SB;
            }
        }

        float4* p = (float4*)(part + (size_t)kc * (NN * 4));
        p[i0] = make_float4(a0, a1, a2, a3);
        p[i1] = make_float4(b0, b1, b2, b3);
    } else {
        // ---------------- spatial conv D, conv W (inline softmax) ----------------
        int h = blockIdx.x;
        int s = tid;                 // s = w*16 + d
        int i = h * 256 + s;

        float4 q = ((const float4*)qin)[i];
        float m = fmaxf(fmaxf(q.x, q.y), fmaxf(q.z, q.w));
        float e0 = EXP2((q.x - m) * L2E), e1 = EXP2((q.y - m) * L2E);
        float e2 = EXP2((q.z - m) * L2E), e3 = EXP2((q.w - m) * L2E);
        float rs = 1.0f / (e0 + e1 + e2 + e3);

        float* A = convL;            // [256][4]
        float* B = convL + 1024;     // [256][4]
        *((float4*)(A + 4 * s)) = make_float4(e0 * rs, e1 * rs, e2 * rs, e3 * rs);
        __syncthreads();

        int w = s >> 4, d = s & 15;
        float t0 = 0, t1 = 0, t2 = 0, t3 = 0;
        #pragma unroll
        for (int dp = 0; dp < DDD; ++dp) {
            float dd = (float)(d - dp);
            float k = EXP2(-dd * dd * C18);
            const float4 v = *((const float4*)(A + 4 * (w * 16 + dp)));
            t0 = fmaf(k, v.x, t0); t1 = fmaf(k, v.y, t1);
            t2 = fmaf(k, v.z, t2); t3 = fmaf(k, v.w, t3);
        }
        *((float4*)(B + 4 * s)) = make_float4(t0, t1, t2, t3);
        __syncthreads();

        float u0 = 0, u1 = 0, u2 = 0, u3 = 0;
        #pragma unroll
        for (int wp = 0; wp < WW; ++wp) {
            float dw = (float)(w - wp);
            float k = EXP2(-dw * dw * C18);
            const float4 v = *((const float4*)(B + 4 * (wp * 16 + d)));
            u0 = fmaf(k, v.x, u0); u1 = fmaf(k, v.y, u1);
            u2 = fmaf(k, v.z, u2); u3 = fmaf(k, v.w, u3);
        }
        *((float4*)(tmp + 4 * i)) = make_float4(u0, u1, u2, u3);
    }
}

// 512 blocks x 256 thr. Block owns 64 idx (= 16 i x 4 c).
// Wave q sums part slices [q*32, q*32+32) + 8 hp of h-conv; LDS combine;
// threads 0..15: normalize + 4x4 matmuls + unary add -> qout.
__global__ __launch_bounds__(256) void reduce_finish(
    const float* __restrict__ part,  // [KS][N*4]
    const float* __restrict__ tmp,   // [N][4] d,w-convolved softmax
    const float* __restrict__ u,
    const float* __restrict__ sk, const float* __restrict__ bk,
    const float* __restrict__ cm,
    float* __restrict__ qout)
{
    int tid = threadIdx.x;
    int q = tid >> 6;                // wave 0..3
    int lane = tid & 63;
    int idx = blockIdx.x * 64 + lane;

    float bl = 0.0f;
    #pragma unroll
    for (int k = 0; k < KS / 4; ++k)
        bl += part[(size_t)(q * (KS / 4) + k) * (NN * 4) + idx];

    int i = idx >> 2;
    int h = i >> 8;
    int scid = idx & 1023;
    float sp = 0.0f;
    #pragma unroll
    for (int k = 0; k < 8; ++k) {
        int hp = q * 8 + k;
        float dh = (float)(h - hp);
        float kk = EXP2(-dh * dh * C18);
        sp = fmaf(kk, tmp[hp * 1024 + scid], sp);
    }

    __shared__ float Lb[4][64];
    __shared__ float Ls[4][64];
    Lb[q][lane] = bl;
    Ls[q][lane] = sp;
    __syncthreads();

    if (tid < 16) {
        float b4[4], s4[4];
        #pragma unroll
        for (int c = 0; c < 4; ++c) {
            int l = tid * 4 + c;
            b4[c] = Lb[0][l] + Lb[1][l] + Lb[2][l] + Lb[3][l];
            s4[c] = Ls[0][l] + Ls[1][l] + Ls[2][l] + Ls[3][l];
        }
        float rb = 1.0f / (b4[0] + b4[1] + b4[2] + b4[3]);
        float rs = 1.0f / (s4[0] + s4[1] + s4[2] + s4[3]);
        float bo[4], so[4];
        #pragma unroll
        for (int c = 0; c < 4; ++c) { bo[c] = b4[c] * rb; so[c] = s4[c] * rs; }
        float msg[4];
        #pragma unroll
        for (int c = 0; c < 4; ++c) {
            float m = 0.0f;
            #pragma unroll
            for (int d = 0; d < 4; ++d)
                m += sk[c * 4 + d] * so[d] + bk[c * 4 + d] * bo[d];
            msg[c] = m;
        }
        int ig = blockIdx.x * 16 + tid;
        #pragma unroll
        for (int c = 0; c < 4; ++c) {
            float pw = 0.0f;
            #pragma unroll
            for (int d = 0; d < 4; ++d) pw += cm[c * 4 + d] * msg[d];
            qout[4 * ig + c] = u[4 * ig + c] + pw;
        }
    }
}

extern "C" void kernel_launch(void* const* d_in, const int* in_sizes, int n_in,
                              void* d_out, int out_size, void* d_ws, size_t ws_size,
                              hipStream_t stream)
{
    const float* u   = (const float*)d_in[0];
    const float* rgb = (const float*)d_in[1];
    const float* sk  = (const float*)d_in[2];
    const float* bk  = (const float*)d_in[3];
    const float* cm  = (const float*)d_in[4];
    float* out = (float*)d_out;

    // ws: part[KS][N*4] (16MB) | tmp[N*4] | qbuf[N*4]
    float* part = (float*)d_ws;
    float* tmpP = part + (size_t)KS * NN * 4;
    float* qbuf = tmpP + (size_t)NN * 4;

    dim3 blk(256);
    dim3 gF(CONVB + GB);         // 32 + 2048
    dim3 gR(NN * 4 / 64);        // 512

    // iteration 1 (q = u)
    fused<<<gF, blk, 0, stream>>>(u, rgb, part, tmpP);
    reduce_finish<<<gR, blk, 0, stream>>>(part, tmpP, u, sk, bk, cm, qbuf);
    // iteration 2
    fused<<<gF, blk, 0, stream>>>(qbuf, rgb, part, tmpP);
    reduce_finish<<<gR, blk, 0, stream>>>(part, tmpP, u, sk, bk, cm, out);
}

// Round 17
// 66.224 us; speedup vs baseline: 3.9282x; 3.9282x over previous
//
#include <hip/hip_runtime.h>

// CRF-RNN mean-field, 2 iterations, N=8192 (32x16x16), C=4.
// Spatial: exactly separable -> 3 dense 1-D convs. Bilateral: N^2, split-K.
// r17 = r16 with the spill fixed: r16's __launch_bounds__(256,8) capped VGPRs
// at 64 and the allocator fell to 32+scratch (measured: VGPR_Count=32,
// FETCH 187MB / WRITE 414MB of spill traffic, VALUBusy 9-17%, 143us/dispatch).
// Fix: (256,4) => 128-VGPR cap (est. need ~60), unroll 16->8.

#define HH 32
#define WW 16
#define DDD 16
#define NN (HH * WW * DDD)    // 8192
#define KS 128                // split-K over j
#define JC (NN / KS)          // 64 j per block (one h-slab quarter: 4 w-groups)
#define CONVB 32
#define GB 2048               // 16 i-tiles (512 rows) x KS
#define L2E 1.4426950408889634f
#define C18 (L2E / 18.0f)     // spatial: exp(-d^2/18) == exp2(-d^2*C18)
#define SQL2E 1.2011224087864498f   // sqrt(log2 e): feats pre-scaled, exp==exp2
#define SB (SQL2E / 8.0f)     // THETA_ALPHA
#define SC (SQL2E / 0.5f)     // THETA_BETA

#if __has_builtin(__builtin_amdgcn_exp2f)
#define EXP2(x) __builtin_amdgcn_exp2f(x)
#else
#define EXP2(x) exp2f(x)
#endif

__device__ __forceinline__ unsigned int cvtpk(float lo, float hi) {
    unsigned int r;
    asm("v_cvt_pk_bf16_f32 %0, %1, %2" : "=v"(r) : "v"(lo), "v"(hi));
    return r;
}
__device__ __forceinline__ float bfLO(unsigned int u) {
    return __uint_as_float(u << 16);
}
__device__ __forceinline__ float bfHI(unsigned int u) {
    return __uint_as_float(u & 0xFFFF0000u);
}

// blocks [0,CONVB): spatial conv D,W (inline softmax).  blocks [CONVB..): bilat.
__global__ __launch_bounds__(256, 4) void fused(
    const float* __restrict__ qin,   // [N][4] current q (u on iter 1)
    const float* __restrict__ rgb,   // [N][3]
    float* __restrict__ part,        // [KS][N*4] bilateral partial numerators
    float* __restrict__ tmp)         // [N][4] d,w-convolved softmax
{
    __shared__ float convL[2048];    // conv: A[1024]|B[1024]
    __shared__ float4 REC[JC];       // bilat: {c0,c1,c2,nj}
    __shared__ uint2  SMA[JC];       // bilat: bf16x4 softmax
    int tid = threadIdx.x;

    if (blockIdx.x >= CONVB) {
        // ---------------- bilateral N^2, 2 rows/thread (h-delta) ----------------
        int b = blockIdx.x - CONVB;
        int ib = b >> 7;                 // 16 i-tiles of 512 rows
        int kc = b & (KS - 1);
        int i0 = ib * 512 + tid;         // h = 2*ib
        int i1 = i0 + 256;               // h = 2*ib + 1
        int j0 = kc * JC;

        // stage 64 j-records (threads 0..63)
        if (tid < JC) {
            int j = j0 + tid;
            int jh = j >> 8, jr = j & 255;
            float gh = (float)(jh + 1) * SB;
            float gw = (float)((jr >> 4) + 1) * SB;
            float gd = (float)((jr & 15) + 1) * SB;
            float e0 = rgb[3 * j + 0] * SC;
            float e1 = rgb[3 * j + 1] * SC;
            float e2 = rgb[3 * j + 2] * SC;
            float nj = -0.5f * (gh * gh + gw * gw + gd * gd +
                                e0 * e0 + e1 * e1 + e2 * e2);
            REC[tid] = make_float4(e0, e1, e2, nj);
            float4 q = ((const float4*)qin)[j];
            float m = fmaxf(fmaxf(q.x, q.y), fmaxf(q.z, q.w));
            float s0 = EXP2((q.x - m) * L2E), s1 = EXP2((q.y - m) * L2E);
            float s2 = EXP2((q.z - m) * L2E), s3 = EXP2((q.w - m) * L2E);
            float rs = 1.0f / (s0 + s1 + s2 + s3);
            SMA[tid] = make_uint2(cvtpk(s0 * rs, s1 * rs), cvtpk(s2 * rs, s3 * rs));
        }

        // i-side constants
        float fw = (float)((tid >> 4) + 1) * SB;
        float fd = (float)((tid & 15) + 1) * SB;
        float fh0 = (float)(2 * ib + 1) * SB;
        float c00 = rgb[3 * i0 + 0] * SC;
        float c01 = rgb[3 * i0 + 1] * SC;
        float c02 = rgb[3 * i0 + 2] * SC;
        float c10 = rgb[3 * i1 + 0] * SC;
        float c11 = rgb[3 * i1 + 1] * SC;
        float c12 = rgb[3 * i1 + 2] * SC;
        float dc0 = c10 - c00, dc1 = c11 - c01, dc2 = c12 - c02;
        float fwd2 = fw * fw + fd * fd;
        float fh1 = fh0 + SB;
        float nn0 = -0.5f * (fh0 * fh0 + fwd2 + c00 * c00 + c01 * c01 + c02 * c02);
        float nn1 = -0.5f * (fh1 * fh1 + fwd2 + c10 * c10 + c11 * c11 + c12 * c12);

        float ghs = (float)((j0 >> 8) + 1) * SB;   // block-uniform j-h feature
        float nnb0 = fmaf(fh0, ghs, nn0);          // base for row 0
        float du = (nn1 - nn0) + SB * ghs;         // row1 = row0 + du + dc.e

        float a0 = 0, a1 = 0, a2 = 0, a3 = 0;
        float b0 = 0, b1 = 0, b2 = 0, b3 = 0;

        __syncthreads();

        int w0g = (j0 >> 4) & 15;
        for (int jw = 0; jw < 4; ++jw) {
            float gws = (float)(w0g + jw + 1) * SB;
            float fwg = fw * gws;
            float gds = SB;
            #pragma unroll 8
            for (int jd = 0; jd < 16; ++jd) {
                int jj = jw * 16 + jd;
                float4 r4 = REC[jj];
                uint2 sp = SMA[jj];
                float g0 = nnb0 + r4.w + fwg;
                g0 = fmaf(fd, gds, g0);
                g0 = fmaf(c00, r4.x, g0);
                g0 = fmaf(c01, r4.y, g0);
                g0 = fmaf(c02, r4.z, g0);
                float g1 = g0 + du;
                g1 = fmaf(dc0, r4.x, g1);
                g1 = fmaf(dc1, r4.y, g1);
                g1 = fmaf(dc2, r4.z, g1);
                float w0 = EXP2(g0);
                float w1 = EXP2(g1);
                float s0 = bfLO(sp.x), s1 = bfHI(sp.x);
                float s2 = bfLO(sp.y), s3 = bfHI(sp.y);
                a0 = fmaf(w0, s0, a0); a1 = fmaf(w0, s1, a1);
                a2 = fmaf(w0, s2, a2); a3 = fmaf(w0, s3, a3);
                b0 = fmaf(w1, s0, b0); b1 = fmaf(w1, s1, b1);
                b2 = fmaf(w1, s2, b2); b3 = fmaf(w1, s3, b3);
                gds += SB;
            }
        }

        float4* p = (float4*)(part + (size_t)kc * (NN * 4));
        p[i0] = make_float4(a0, a1, a2, a3);
        p[i1] = make_float4(b0, b1, b2, b3);
    } else {
        // ---------------- spatial conv D, conv W (inline softmax) ----------------
        int h = blockIdx.x;
        int s = tid;                 // s = w*16 + d
        int i = h * 256 + s;

        float4 q = ((const float4*)qin)[i];
        float m = fmaxf(fmaxf(q.x, q.y), fmaxf(q.z, q.w));
        float e0 = EXP2((q.x - m) * L2E), e1 = EXP2((q.y - m) * L2E);
        float e2 = EXP2((q.z - m) * L2E), e3 = EXP2((q.w - m) * L2E);
        float rs = 1.0f / (e0 + e1 + e2 + e3);

        float* A = convL;            // [256][4]
        float* B = convL + 1024;     // [256][4]
        *((float4*)(A + 4 * s)) = make_float4(e0 * rs, e1 * rs, e2 * rs, e3 * rs);
        __syncthreads();

        int w = s >> 4, d = s & 15;
        float t0 = 0, t1 = 0, t2 = 0, t3 = 0;
        #pragma unroll
        for (int dp = 0; dp < DDD; ++dp) {
            float dd = (float)(d - dp);
            float k = EXP2(-dd * dd * C18);
            const float4 v = *((const float4*)(A + 4 * (w * 16 + dp)));
            t0 = fmaf(k, v.x, t0); t1 = fmaf(k, v.y, t1);
            t2 = fmaf(k, v.z, t2); t3 = fmaf(k, v.w, t3);
        }
        *((float4*)(B + 4 * s)) = make_float4(t0, t1, t2, t3);
        __syncthreads();

        float u0 = 0, u1 = 0, u2 = 0, u3 = 0;
        #pragma unroll
        for (int wp = 0; wp < WW; ++wp) {
            float dw = (float)(w - wp);
            float k = EXP2(-dw * dw * C18);
            const float4 v = *((const float4*)(B + 4 * (wp * 16 + d)));
            u0 = fmaf(k, v.x, u0); u1 = fmaf(k, v.y, u1);
            u2 = fmaf(k, v.z, u2); u3 = fmaf(k, v.w, u3);
        }
        *((float4*)(tmp + 4 * i)) = make_float4(u0, u1, u2, u3);
    }
}

// 512 blocks x 256 thr. Block owns 64 idx (= 16 i x 4 c).
// Wave q sums part slices [q*32, q*32+32) + 8 hp of h-conv; LDS combine;
// threads 0..15: normalize + 4x4 matmuls + unary add -> qout.
__global__ __launch_bounds__(256) void reduce_finish(
    const float* __restrict__ part,  // [KS][N*4]
    const float* __restrict__ tmp,   // [N][4] d,w-convolved softmax
    const float* __restrict__ u,
    const float* __restrict__ sk, const float* __restrict__ bk,
    const float* __restrict__ cm,
    float* __restrict__ qout)
{
    int tid = threadIdx.x;
    int q = tid >> 6;                // wave 0..3
    int lane = tid & 63;
    int idx = blockIdx.x * 64 + lane;

    float bl = 0.0f;
    #pragma unroll
    for (int k = 0; k < KS / 4; ++k)
        bl += part[(size_t)(q * (KS / 4) + k) * (NN * 4) + idx];

    int i = idx >> 2;
    int h = i >> 8;
    int scid = idx & 1023;
    float sp = 0.0f;
    #pragma unroll
    for (int k = 0; k < 8; ++k) {
        int hp = q * 8 + k;
        float dh = (float)(h - hp);
        float kk = EXP2(-dh * dh * C18);
        sp = fmaf(kk, tmp[hp * 1024 + scid], sp);
    }

    __shared__ float Lb[4][64];
    __shared__ float Ls[4][64];
    Lb[q][lane] = bl;
    Ls[q][lane] = sp;
    __syncthreads();

    if (tid < 16) {
        float b4[4], s4[4];
        #pragma unroll
        for (int c = 0; c < 4; ++c) {
            int l = tid * 4 + c;
            b4[c] = Lb[0][l] + Lb[1][l] + Lb[2][l] + Lb[3][l];
            s4[c] = Ls[0][l] + Ls[1][l] + Ls[2][l] + Ls[3][l];
        }
        float rb = 1.0f / (b4[0] + b4[1] + b4[2] + b4[3]);
        float rs = 1.0f / (s4[0] + s4[1] + s4[2] + s4[3]);
        float bo[4], so[4];
        #pragma unroll
        for (int c = 0; c < 4; ++c) { bo[c] = b4[c] * rb; so[c] = s4[c] * rs; }
        float msg[4];
        #pragma unroll
        for (int c = 0; c < 4; ++c) {
            float m = 0.0f;
            #pragma unroll
            for (int d = 0; d < 4; ++d)
                m += sk[c * 4 + d] * so[d] + bk[c * 4 + d] * bo[d];
            msg[c] = m;
        }
        int ig = blockIdx.x * 16 + tid;
        #pragma unroll
        for (int c = 0; c < 4; ++c) {
            float pw = 0.0f;
            #pragma unroll
            for (int d = 0; d < 4; ++d) pw += cm[c * 4 + d] * msg[d];
            qout[4 * ig + c] = u[4 * ig + c] + pw;
        }
    }
}

extern "C" void kernel_launch(void* const* d_in, const int* in_sizes, int n_in,
                              void* d_out, int out_size, void* d_ws, size_t ws_size,
                              hipStream_t stream)
{
    const float* u   = (const float*)d_in[0];
    const float* rgb = (const float*)d_in[1];
    const float* sk  = (const float*)d_in[2];
    const float* bk  = (const float*)d_in[3];
    const float* cm  = (const float*)d_in[4];
    float* out = (float*)d_out;

    // ws: part[KS][N*4] (16MB) | tmp[N*4] | qbuf[N*4]
    float* part = (float*)d_ws;
    float* tmpP = part + (size_t)KS * NN * 4;
    float* qbuf = tmpP + (size_t)NN * 4;

    dim3 blk(256);
    dim3 gF(CONVB + GB);         // 32 + 2048
    dim3 gR(NN * 4 / 64);        // 512

    // iteration 1 (q = u)
    fused<<<gF, blk, 0, stream>>>(u, rgb, part, tmpP);
    reduce_finish<<<gR, blk, 0, stream>>>(part, tmpP, u, sk, bk, cm, qbuf);
    // iteration 2
    fused<<<gF, blk, 0, stream>>>(qbuf, rgb, part, tmpP);
    reduce_finish<<<gR, blk, 0, stream>>>(part, tmpP, u, sk, bk, cm, out);
}